// Round 1
// 259.531 us; speedup vs baseline: 1.0416x; 1.0416x over previous
//
#include <hip/hip_runtime.h>

// Problem constants: B=4, M=512, L=31, S=2, W=M+L-1=542
#define CB 4
#define CM 512
#define CL 31
#define CW 542
#define SLAB  (CM * CL)      // 15872 floats of H per (b,m) slab
#define SLAB4 (SLAB / 4)     // 3968 float4
#define NBM   (CB * CM)      // 2048 slabs
#define CPAD  543            // ysum copy stride (543 mod 32 = 31 -> bank-spread)

// X[b,m,n,l] = H[b,m,n,l] * (Y[b,m,n+l,0] + Y[b,m,n+l,1]); out = X / max(X)
// One block per (b,m) slab, 256 threads, H/out streamed as float4.
//
// ysum is staged as FOUR replicated copies at stride 543 floats; lane uses
// copy (tid>>3)&3. The stride-4 gather then hits each bank with exactly 2
// lanes (2-way == free) instead of ~4-way on a single copy.
//
// Index math: thread's flat offset f = 4*tid + 1024*k. 1024 = 33*31 + 1, so
// l = f%31 advances +1 per iteration; carry (l0, i0=n0+l0) incrementally.
// No integer division inside the loop.

__device__ __forceinline__ void stage_ysum(const float* __restrict__ Y, int bm,
                                           float* __restrict__ ys) {
    const float2* y2 = (const float2*)(Y + (size_t)bm * (CW * 2));
    for (int j = threadIdx.x; j < CW; j += 256) {
        float2 v = y2[j];
        float s = v.x + v.y;
        ys[j]            = s;
        ys[j + CPAD]     = s;
        ys[j + 2 * CPAD] = s;
        ys[j + 3 * CPAD] = s;
    }
}

struct IdxState {
    int l0;   // f % 31 for the quad base
    int i0;   // n0 + l0  (the ysum index of the quad's first element)
};

__device__ __forceinline__ IdxState idx_init(int tid) {
    unsigned f = 4u * (unsigned)tid;
    unsigned n = f / 31u;            // one division, outside the loop
    IdxState s;
    s.l0 = (int)(f - n * 31u);
    s.i0 = (int)n + s.l0;
    return s;
}

__device__ __forceinline__ void idx_quad(const IdxState& s,
                                         int& i0, int& i1, int& i2, int& i3) {
    // element j wraps iff l0 >= 31-j (at most one wrap inside a quad, L=31>4)
    i0 = s.i0;
    i1 = s.i0 + ((s.l0 >= 30) ? 1 - 30 : 1);
    i2 = s.i0 + ((s.l0 >= 29) ? 2 - 30 : 2);
    i3 = s.i0 + ((s.l0 >= 28) ? 3 - 30 : 3);
}

__device__ __forceinline__ void idx_step(IdxState& s) {
    // f += 1024 = 33*31 + 1  ->  l0 += 1 (mod 31); i0 += 34 (or +4 on wrap)
    bool w = (s.l0 == 30);
    s.i0 += w ? 4 : 34;
    s.l0  = w ? 0 : (s.l0 + 1);
}

__global__ __launch_bounds__(256, 8) void cassi_max(
    const float* __restrict__ Y,
    const float* __restrict__ H,
    float* __restrict__ blockmax)
{
    __shared__ float ysum[4 * CPAD];
    __shared__ float smax[4];
    const int bm  = blockIdx.x;
    const int tid = threadIdx.x;

    stage_ysum(Y, bm, ysum);
    __syncthreads();

    const float* ys = ysum + ((tid >> 3) & 3) * CPAD;
    const float4* h4 = (const float4*)(H + (size_t)bm * SLAB);

    IdxState st = idx_init(tid);
    float mx = 0.0f;   // all X >= 0 (H,Y uniform [0,1))

#pragma unroll 5
    for (int k = 0; k < 15; ++k) {
        float4 h = h4[tid + (k << 8)];
        int i0, i1, i2, i3;
        idx_quad(st, i0, i1, i2, i3);
        float v0 = h.x * ys[i0];
        float v1 = h.y * ys[i1];
        float v2 = h.z * ys[i2];
        float v3 = h.w * ys[i3];
        mx = fmaxf(mx, fmaxf(fmaxf(v0, v1), fmaxf(v2, v3)));
        idx_step(st);
    }
    if (tid < 128) {   // tail half-pass: SLAB4 = 15.5 * 256
        float4 h = h4[tid + 15 * 256];
        int i0, i1, i2, i3;
        idx_quad(st, i0, i1, i2, i3);
        float v0 = h.x * ys[i0];
        float v1 = h.y * ys[i1];
        float v2 = h.z * ys[i2];
        float v3 = h.w * ys[i3];
        mx = fmaxf(mx, fmaxf(fmaxf(v0, v1), fmaxf(v2, v3)));
    }

#pragma unroll
    for (int off = 32; off > 0; off >>= 1)
        mx = fmaxf(mx, __shfl_down(mx, off, 64));
    if ((tid & 63) == 0) smax[tid >> 6] = mx;
    __syncthreads();
    if (tid == 0)
        blockmax[bm] = fmaxf(fmaxf(smax[0], smax[1]), fmaxf(smax[2], smax[3]));
}

__global__ __launch_bounds__(256, 8) void cassi_out(
    const float* __restrict__ Y,
    const float* __restrict__ H,
    const float* __restrict__ blockmax,
    float* __restrict__ out)
{
    __shared__ float ysum[4 * CPAD];
    __shared__ float sm[4];
    const int bm  = blockIdx.x;
    const int tid = threadIdx.x;

    stage_ysum(Y, bm, ysum);

    // global max = reduce of 2048 per-block maxima (L2-broadcast, ~8 loads/thr)
    float m = 0.0f;
    for (int j = tid; j < NBM; j += 256) m = fmaxf(m, blockmax[j]);
#pragma unroll
    for (int off = 32; off > 0; off >>= 1)
        m = fmaxf(m, __shfl_down(m, off, 64));
    if ((tid & 63) == 0) sm[tid >> 6] = m;
    __syncthreads();   // covers both ysum and sm stores
    const float inv = 1.0f / fmaxf(fmaxf(sm[0], sm[1]), fmaxf(sm[2], sm[3]));

    const float* ys = ysum + ((tid >> 3) & 3) * CPAD;
    const float4* h4 = (const float4*)(H + (size_t)bm * SLAB);
    float4* o4 = (float4*)(out + (size_t)bm * SLAB);

    IdxState st = idx_init(tid);

#pragma unroll 5
    for (int k = 0; k < 15; ++k) {
        float4 h = h4[tid + (k << 8)];
        int i0, i1, i2, i3;
        idx_quad(st, i0, i1, i2, i3);
        float4 o;
        o.x = h.x * ys[i0] * inv;
        o.y = h.y * ys[i1] * inv;
        o.z = h.z * ys[i2] * inv;
        o.w = h.w * ys[i3] * inv;
        o4[tid + (k << 8)] = o;
        idx_step(st);
    }
    if (tid < 128) {
        float4 h = h4[tid + 15 * 256];
        int i0, i1, i2, i3;
        idx_quad(st, i0, i1, i2, i3);
        float4 o;
        o.x = h.x * ys[i0] * inv;
        o.y = h.y * ys[i1] * inv;
        o.z = h.z * ys[i2] * inv;
        o.w = h.w * ys[i3] * inv;
        o4[tid + 15 * 256] = o;
    }
}

extern "C" void kernel_launch(void* const* d_in, const int* in_sizes, int n_in,
                              void* d_out, int out_size, void* d_ws, size_t ws_size,
                              hipStream_t stream)
{
    const float* Y = (const float*)d_in[0];   // (B, M, W, S)
    const float* H = (const float*)d_in[1];   // (B, M, M, L)
    float* out = (float*)d_out;               // (B, M, M, L)
    float* blockmax = (float*)d_ws;           // 2048 floats; fully written each
                                              // launch before being read -> no memset

    cassi_max<<<NBM, 256, 0, stream>>>(Y, H, blockmax);
    cassi_out<<<NBM, 256, 0, stream>>>(Y, H, blockmax, out);
}